// Round 14
// baseline (245.379 us; speedup 1.0000x reference)
//
#include <hip/hip_runtime.h>
#include <hip/hip_bf16.h>

#define B_ 32
#define T_ 512
#define TP_ 514          /* padded rows per batch */
#define L_ 2048
#define H_ 512
#define NRR (B_*T_)      /* 16384 rows */
#define KC_ 1536         /* 3*H */
#define NB_ 256
#define EPS_ 1e-5f
#define XPE ((size_t)B_ * TP_ * H_)   /* elems per padded buffer */

typedef __bf16 bf16;
typedef __bf16 bf16x8 __attribute__((ext_vector_type(8)));
typedef float f32x4 __attribute__((ext_vector_type(4)));

static const size_t WC_BYTES  = (size_t)6 * H_ * KC_ * 2;       // 9,437,184
static const size_t XP_BYTES  = XPE * 2;                        // 16,842,752
static const size_t Y_BYTES   = (size_t)3 * NRR * H_ * 2;       // 50,331,648

__device__ __forceinline__ void gload16(const void* g, void* l) {
    __builtin_amdgcn_global_load_lds(
        (const __attribute__((address_space(1))) unsigned int*)g,
        (__attribute__((address_space(3))) unsigned int*)l, 16, 0, 0);
}

// ---------------- weight repack: w[i][o][c][k] -> Wc[m][o][k*H + c] (bf16) ----
__global__ void k_prep_wc(const float* __restrict__ wd, const float* __restrict__ wp,
                          const float* __restrict__ we, bf16* __restrict__ wc) {
    int e = blockIdx.x * 256 + threadIdx.x;
    if (e >= 6 * H_ * KC_) return;
    int m   = e / (H_ * KC_);
    int rem = e % (H_ * KC_);
    int o  = rem / KC_;
    int r2 = rem % KC_;
    int k  = r2 / H_;
    int c  = r2 % H_;
    int p = m >> 1, i = m & 1;
    const float* w = (p == 0) ? wd : (p == 1 ? wp : we);
    float v = w[((size_t)i * H_ * H_ + (size_t)o * H_ + c) * 3 + k];
    wc[e] = (bf16)v;
}

// ---------------- padded bf16 input + zero pad rows of the 3 xp1 buffers -----
__global__ void k_pad(const float* __restrict__ x, bf16* __restrict__ xp0,
                      bf16* __restrict__ xp1) {
    int wid = threadIdx.x >> 6, lane = threadIdx.x & 63;
    int row = blockIdx.x * 4 + wid;               // 0 .. 32*514-1
    int b = row / TP_, tp = row % TP_;
    bf16* d0 = xp0 + (size_t)row * H_ + lane * 8;
    if (tp == 0 || tp == TP_ - 1) {
        bf16x8 z;
#pragma unroll
        for (int i = 0; i < 8; ++i) z[i] = (bf16)0.0f;
        *(bf16x8*)d0 = z;
#pragma unroll
        for (int p = 0; p < 3; ++p)
            *(bf16x8*)(xp1 + p * XPE + (size_t)row * H_ + lane * 8) = z;
    } else {
        const f32x4* p = (const f32x4*)(x + ((size_t)(b * T_ + tp - 1)) * H_ + lane * 8);
        f32x4 u = p[0], v = p[1];
        bf16x8 o;
        o[0] = (bf16)u[0]; o[1] = (bf16)u[1]; o[2] = (bf16)u[2]; o[3] = (bf16)u[3];
        o[4] = (bf16)v[0]; o[5] = (bf16)v[1]; o[6] = (bf16)v[2]; o[7] = (bf16)v[3];
        *(bf16x8*)d0 = o;
    }
}

// ---------------- per-batch inclusive scan of durations ----------------------
__global__ void k_scan(const int* __restrict__ dur, int* __restrict__ csum,
                       float* __restrict__ mel_out) {
    int b = blockIdx.x, t = threadIdx.x;
    __shared__ int s[T_];
    s[t] = dur[b * T_ + t];
    __syncthreads();
    for (int off = 1; off < T_; off <<= 1) {
        int v = (t >= off) ? s[t - off] : 0;
        __syncthreads();
        s[t] += v;
        __syncthreads();
    }
    csum[b * T_ + t] = s[t];
    if (t == T_ - 1) mel_out[b] = (float)((s[t] < L_) ? s[t] : L_);
}

// -------- length regulate + inline bucketize + (x + p_emb + e_emb) gather ----
__global__ void k_gather(const float* __restrict__ x, const float* __restrict__ pemb,
                         const float* __restrict__ eemb, const float* __restrict__ pt,
                         const float* __restrict__ et, const float* __restrict__ pbins,
                         const float* __restrict__ ebins, const int* __restrict__ csum,
                         float* __restrict__ out) {
    int bi = blockIdx.x;
    int b  = bi >> 9;
    int l0 = (bi & 511) << 2;
    __shared__ int cs[T_];
    __shared__ float pb[NB_ - 1], eb[NB_ - 1];
    cs[threadIdx.x]       = csum[b * T_ + threadIdx.x];
    cs[threadIdx.x + 256] = csum[b * T_ + threadIdx.x + 256];
    if (threadIdx.x < NB_ - 1) {
        pb[threadIdx.x] = pbins[threadIdx.x];
        eb[threadIdx.x] = ebins[threadIdx.x];
    }
    __syncthreads();
    int wid = threadIdx.x >> 6, lane = threadIdx.x & 63;
    int l = l0 + wid;
    int mel = cs[T_ - 1]; if (mel > L_) mel = L_;
    float* op = out + ((size_t)(b * L_ + l)) * H_ + lane * 8;
    if (l >= mel) {
        f32x4 z = {0.f, 0.f, 0.f, 0.f};
        ((f32x4*)op)[0] = z;
        ((f32x4*)op)[1] = z;
        return;
    }
    int lo = 0, hi = T_;
    while (lo < hi) { int mid = (lo + hi) >> 1; if (cs[mid] <= l) lo = mid + 1; else hi = mid; }
    int idx = (lo < T_ - 1) ? lo : (T_ - 1);
    int rr = b * T_ + idx;
    float pv = pt[rr], ev = et[rr];
    int pi, ei;
    { int a = 0, c = NB_ - 1; while (a < c) { int mid = (a + c) >> 1; if (pb[mid] < pv) a = mid + 1; else c = mid; } pi = a; }
    { int a = 0, c = NB_ - 1; while (a < c) { int mid = (a + c) >> 1; if (eb[mid] < ev) a = mid + 1; else c = mid; } ei = a; }
    const f32x4* xp = (const f32x4*)(x    + (size_t)rr * H_ + lane * 8);
    const f32x4* pp = (const f32x4*)(pemb + (size_t)pi * H_ + lane * 8);
    const f32x4* ep = (const f32x4*)(eemb + (size_t)ei * H_ + lane * 8);
    ((f32x4*)op)[0] = xp[0] + pp[0] + ep[0];
    ((f32x4*)op)[1] = xp[1] + pp[1] + ep[1];
}

// ============ conv-aware tiled GEMM with tap-reuse (R8-verified optimum) =====
// BM=128, BN=128, H-chunk=64; 4 waves (2Mx2N), per-wave 64x64 out.
// A staged ONCE per H-chunk as a 136-row slab; 3 conv taps read row-shifted
// fragments from the same LDS tile. T2 both-sides swizzle; T1 XCD map.
// LAYER 0: epilogue = bias+relu -> y (bf16).
// LAYER 1: epilogue = per-row partials (S, Q, P=sum v*g*w) for the fused
//          LN+linear -> part[p][row][piece][3]; no y write.
template<int LAYER>
__global__ __launch_bounds__(256)
void k_gemm(const bf16* __restrict__ Xp, const bf16* __restrict__ Wall,
            const float* __restrict__ cb0, const float* __restrict__ cb1,
            const float* __restrict__ cb2,
            const float* __restrict__ g0, const float* __restrict__ g1,
            const float* __restrict__ g2,
            const float* __restrict__ w0p, const float* __restrict__ w1p,
            const float* __restrict__ w2p,
            bf16* __restrict__ Y, float* __restrict__ part) {
    __shared__ bf16 lA[136 * 64];        // 17,408 B
    __shared__ bf16 lB[3 * 128 * 64];    // 49,152 B

    int bid = blockIdx.x;
    int xcd = bid & 7, idx = bid >> 3;   // 1536 blocks: idx 0..191
    int colblk = idx >> 4;               // 0..11  (colblk-major per XCD)
    int rowblk = xcd * 16 + (idx & 15);  // 0..127
    int p  = colblk >> 2;
    int oB = (colblk & 3) * 128;
    int rowBase = rowblk * 128;

    const bf16* A = (LAYER == 0) ? Xp : (Xp + (size_t)p * XPE);
    const bf16* W = Wall + ((size_t)(2 * p + LAYER) * H_ + oB) * KC_;
    const float* cbp  = (p == 0) ? cb0 : (p == 1 ? cb1 : cb2);
    const float* bias = cbp + LAYER * H_;

    int tid = threadIdx.x;
    int wid = tid >> 6, lane = tid & 63;
    int wm = wid >> 1, wn = wid & 1;     // 2M x 2N waves
    int lr = lane & 15, kq = lane >> 4;
    int rsub = lane >> 3;
    int csw  = ((lane & 7) ^ rsub) << 3; // T2 pre-swizzled source col (16B units)
    int b = rowBase >> 9, t0 = rowBase & (T_ - 1);
    const bf16* Abase = A + ((size_t)(b * TP_ + t0)) * H_;

    f32x4 acc[4][4];
#pragma unroll
    for (int m = 0; m < 4; ++m)
#pragma unroll
        for (int n = 0; n < 4; ++n) acc[m][n] = (f32x4){0.f, 0.f, 0.f, 0.f};

    for (int s = 0; s < 8; ++s) {
        int c0 = s * 64;
        // ---- stage A: 17 groups of 8 rows (136 rows) ----
#pragma unroll
        for (int q = 0; q < 5; ++q) {
            int g = q * 4 + wid;
            if (g < 17)
                gload16(Abase + (size_t)(g * 8 + rsub) * H_ + c0 + csw, &lA[g * 8 * 64]);
        }
        // ---- stage B: 3 taps x 16 groups of 8 rows ----
#pragma unroll
        for (int tap = 0; tap < 3; ++tap)
#pragma unroll
            for (int q = 0; q < 4; ++q) {
                int g = q * 4 + wid;
                gload16(W + (size_t)(g * 8 + rsub) * KC_ + tap * H_ + c0 + csw,
                        &lB[(tap * 128 + g * 8) * 64]);
            }
        __syncthreads();   // compiler drains vmcnt before barrier

#pragma unroll
        for (int tap = 0; tap < 3; ++tap) {
            bf16x8 af[4][2], bfr[4][2];
            int ka = (lr + tap) & 7, kb = lr & 7;
#pragma unroll
            for (int m = 0; m < 4; ++m)
#pragma unroll
                for (int kk = 0; kk < 2; ++kk)
                    af[m][kk] = *(const bf16x8*)&lA[(wm * 64 + m * 16 + lr + tap) * 64 +
                                                    ((((kk * 4 + kq) ^ ka)) << 3)];
#pragma unroll
            for (int n = 0; n < 4; ++n)
#pragma unroll
                for (int kk = 0; kk < 2; ++kk)
                    bfr[n][kk] = *(const bf16x8*)&lB[(tap * 128 + wn * 64 + n * 16 + lr) * 64 +
                                                     ((((kk * 4 + kq) ^ kb)) << 3)];
#pragma unroll
            for (int m = 0; m < 4; ++m)
#pragma unroll
                for (int n = 0; n < 4; ++n)
#pragma unroll
                    for (int kk = 0; kk < 2; ++kk)
                        acc[m][n] = __builtin_amdgcn_mfma_f32_16x16x32_bf16(
                            af[m][kk], bfr[n][kk], acc[m][n], 0, 0, 0);
        }
        __syncthreads();
    }

    if constexpr (LAYER == 0) {
        // D layout: col = lane&15 (o), row = 4*(lane>>4) + reg
#pragma unroll
        for (int n = 0; n < 4; ++n) {
            int o = oB + wn * 64 + n * 16 + lr;
            float bi = bias[o];
#pragma unroll
            for (int m = 0; m < 4; ++m) {
                int row = rowBase + wm * 64 + m * 16 + 4 * kq;
#pragma unroll
                for (int r = 0; r < 4; ++r)
                    Y[((size_t)p * NRR + row + r) * H_ + o] = (bf16)fmaxf(acc[m][n][r] + bi, 0.f);
            }
        }
    } else {
        // fused LN+linear partials: per row S=sum v, Q=sum v^2, P=sum v*g*w
        const float* gp  = ((p == 0) ? g0 : (p == 1 ? g1 : g2)) + H_;
        const float* lwp = (p == 0) ? w0p : (p == 1 ? w1p : w2p);
        float bc[4], gc[4], wc4[4];
#pragma unroll
        for (int n = 0; n < 4; ++n) {
            int col = oB + wn * 64 + n * 16 + lr;
            bc[n] = bias[col]; gc[n] = gp[col]; wc4[n] = lwp[col];
        }
        float* red = (float*)lA;    // [128][2][3] floats; safe after final barrier
#pragma unroll
        for (int m = 0; m < 4; ++m)
#pragma unroll
            for (int r = 0; r < 4; ++r) {
                float s = 0.f, q = 0.f, pw = 0.f;
#pragma unroll
                for (int n = 0; n < 4; ++n) {
                    float v = fmaxf(acc[m][n][r] + bc[n], 0.f);
                    s += v; q += v * v; pw += v * gc[n] * wc4[n];
                }
#pragma unroll
                for (int msk = 1; msk < 16; msk <<= 1) {
                    s  += __shfl_xor(s,  msk);
                    q  += __shfl_xor(q,  msk);
                    pw += __shfl_xor(pw, msk);
                }
                if (lr == 0) {
                    int rl = wm * 64 + m * 16 + 4 * kq + r;
                    red[(rl * 2 + wn) * 3 + 0] = s;
                    red[(rl * 2 + wn) * 3 + 1] = q;
                    red[(rl * 2 + wn) * 3 + 2] = pw;
                }
            }
        __syncthreads();
        if (tid < 128) {
            float S = red[tid * 6 + 0] + red[tid * 6 + 3];
            float Q = red[tid * 6 + 1] + red[tid * 6 + 4];
            float P = red[tid * 6 + 2] + red[tid * 6 + 5];
            float* dst = part + ((size_t)(p * NRR + rowBase + tid) * 4 + (colblk & 3)) * 3;
            dst[0] = S; dst[1] = Q; dst[2] = P;
        }
    }
}

// ---------------- batched LayerNorm (layer-0) -> padded xp1[p] ---------------
__global__ void k_ln_store(const bf16* __restrict__ Yin,
                           const float* __restrict__ g0, const float* __restrict__ g1,
                           const float* __restrict__ g2,
                           const float* __restrict__ bb0, const float* __restrict__ bb1,
                           const float* __restrict__ bb2, bf16* __restrict__ xp1) {
    int wid = threadIdx.x >> 6, lane = threadIdx.x & 63;
    int rg = blockIdx.x * 4 + wid;
    int p = rg >> 14, r = rg & (NRR - 1);
    const float* g   = (p == 0) ? g0 : (p == 1 ? g1 : g2);
    const float* bta = (p == 0) ? bb0 : (p == 1 ? bb1 : bb2);
    bf16x8 a = *(const bf16x8*)(Yin + ((size_t)p * NRR + r) * H_ + lane * 8);
    float f[8];
#pragma unroll
    for (int i = 0; i < 8; ++i) f[i] = (float)a[i];
    float s1 = 0.f, s2 = 0.f;
#pragma unroll
    for (int i = 0; i < 8; ++i) { s1 += f[i]; s2 += f[i] * f[i]; }
    for (int m = 1; m < 64; m <<= 1) { s1 += __shfl_xor(s1, m); s2 += __shfl_xor(s2, m); }
    float mean = s1 * (1.f / H_);
    float var  = s2 * (1.f / H_) - mean * mean;
    float rs   = rsqrtf(var + EPS_);
    const f32x4* gp = (const f32x4*)g;
    const f32x4* bp = (const f32x4*)bta;
    f32x4 ga = gp[lane * 2], gb = gp[lane * 2 + 1];
    f32x4 ba = bp[lane * 2], bbv = bp[lane * 2 + 1];
    bf16x8 o;
    o[0] = (bf16)((f[0] - mean) * rs * ga[0] + ba[0]);
    o[1] = (bf16)((f[1] - mean) * rs * ga[1] + ba[1]);
    o[2] = (bf16)((f[2] - mean) * rs * ga[2] + ba[2]);
    o[3] = (bf16)((f[3] - mean) * rs * ga[3] + ba[3]);
    o[4] = (bf16)((f[4] - mean) * rs * gb[0] + bbv[0]);
    o[5] = (bf16)((f[5] - mean) * rs * gb[1] + bbv[1]);
    o[6] = (bf16)((f[6] - mean) * rs * gb[2] + bbv[2]);
    o[7] = (bf16)((f[7] - mean) * rs * gb[3] + bbv[3]);
    int bb = r >> 9, t = r & (T_ - 1);
    *(bf16x8*)(xp1 + (size_t)p * XPE + ((size_t)(bb * TP_ + t + 1)) * H_ + lane * 8) = o;
}

// ---------------- finish fused LN+linear from partials -----------------------
// out = rs*(P - mean*G) + Bc + lb ;  G = sum g*w, Bc = sum beta*w (per p)
__global__ void k_fin(const float* __restrict__ part,
                      const float* __restrict__ g0, const float* __restrict__ g1,
                      const float* __restrict__ g2,
                      const float* __restrict__ bb0, const float* __restrict__ bb1,
                      const float* __restrict__ bb2,
                      const float* __restrict__ w0p, const float* __restrict__ w1p,
                      const float* __restrict__ w2p,
                      const float* __restrict__ lb0, const float* __restrict__ lb1,
                      const float* __restrict__ lb2,
                      const unsigned char* __restrict__ mask,
                      float* __restrict__ o0, float* __restrict__ o1,
                      float* __restrict__ o2) {
    int blk = blockIdx.x;            // 192 blocks: 64 per predictor
    int p = blk >> 6;
    int r0 = (blk & 63) * 256;
    const float* g  = ((p == 0) ? g0 : (p == 1 ? g1 : g2)) + H_;
    const float* bt = ((p == 0) ? bb0 : (p == 1 ? bb1 : bb2)) + H_;
    const float* w  = (p == 0) ? w0p : (p == 1 ? w1p : w2p);
    const float* lb = (p == 0) ? lb0 : (p == 1 ? lb1 : lb2);
    float* op       = (p == 0) ? o0 : (p == 1 ? o1 : o2);

    __shared__ float sG[4], sB[4];
    int tid = threadIdx.x, lane = tid & 63, wid = tid >> 6;
    float gs = g[tid] * w[tid] + g[tid + 256] * w[tid + 256];
    float bs = bt[tid] * w[tid] + bt[tid + 256] * w[tid + 256];
    for (int m = 1; m < 64; m <<= 1) { gs += __shfl_xor(gs, m); bs += __shfl_xor(bs, m); }
    if (lane == 0) { sG[wid] = gs; sB[wid] = bs; }
    __syncthreads();
    float G  = sG[0] + sG[1] + sG[2] + sG[3];
    float Bc = sB[0] + sB[1] + sB[2] + sB[3];

    int r = r0 + tid;
    const float* pr = part + ((size_t)(p * NRR + r) * 4) * 3;
    float S = pr[0] + pr[3] + pr[6] + pr[9];
    float Q = pr[1] + pr[4] + pr[7] + pr[10];
    float P = pr[2] + pr[5] + pr[8] + pr[11];
    float mean = S * (1.f / H_);
    float var  = Q * (1.f / H_) - mean * mean;
    float rs   = rsqrtf(var + EPS_);
    float val  = rs * (P - mean * G) + Bc + lb[0];
    op[r] = mask[r] ? 0.f : val;
}

extern "C" void kernel_launch(void* const* d_in, const int* in_sizes, int n_in,
                              void* d_out, int out_size, void* d_ws, size_t ws_size,
                              hipStream_t stream) {
    const float* x  = (const float*)d_in[0];
    const unsigned char* mask = (const unsigned char*)d_in[1];
    const int*   dur = (const int*)d_in[2];
    const float* pt  = (const float*)d_in[3];
    const float* et  = (const float*)d_in[4];
    const float* cw[3]    = {(const float*)d_in[6],  (const float*)d_in[12], (const float*)d_in[18]};
    const float* cb[3]    = {(const float*)d_in[7],  (const float*)d_in[13], (const float*)d_in[19]};
    const float* lg[3]    = {(const float*)d_in[8],  (const float*)d_in[14], (const float*)d_in[20]};
    const float* lbn[3]   = {(const float*)d_in[9],  (const float*)d_in[15], (const float*)d_in[21]};
    const float* lw[3]    = {(const float*)d_in[10], (const float*)d_in[16], (const float*)d_in[22]};
    const float* lbias[3] = {(const float*)d_in[11], (const float*)d_in[17], (const float*)d_in[23]};
    const float* pbins = (const float*)d_in[24];
    const float* ebins = (const float*)d_in[25];
    const float* pemb  = (const float*)d_in[26];
    const float* eemb  = (const float*)d_in[27];

    float* out0 = (float*)d_out;
    const size_t OUT0 = (size_t)B_ * L_ * H_;
    float* pitch_out  = out0 + OUT0;
    float* energy_out = pitch_out + NRR;
    float* logd_out   = energy_out + NRR;
    float* mel_out    = logd_out + NRR;

    char* ws = (char*)d_ws;
    bf16*  wc   = (bf16*)ws;
    bf16*  xp0  = (bf16*)(ws + WC_BYTES);
    bf16*  xp1  = (bf16*)(ws + WC_BYTES + XP_BYTES);          // 3 buffers
    bf16*  y    = (bf16*)(ws + WC_BYTES + 4 * XP_BYTES);      // [3][NRR][512]
    int*   csum = (int*)(ws + WC_BYTES + 4 * XP_BYTES + Y_BYTES);
    float* part = (float*)(csum + NRR);                       // [3][NRR][4][3]

    k_prep_wc<<<(6 * H_ * KC_ + 255) / 256, 256, 0, stream>>>(cw[0], cw[1], cw[2], wc);
    k_pad<<<B_ * TP_ / 4, 256, 0, stream>>>(x, xp0, xp1);
    k_scan<<<B_, T_, 0, stream>>>(dur, csum, mel_out);
    k_gather<<<B_ * L_ / 4, 256, 0, stream>>>(x, pemb, eemb, pt, et, pbins, ebins, csum, out0);

    k_gemm<0><<<1536, 256, 0, stream>>>(xp0, wc, cb[0], cb[1], cb[2],
                                        lg[0], lg[1], lg[2], lw[0], lw[1], lw[2],
                                        y, part);
    k_ln_store<<<3 * NRR / 4, 256, 0, stream>>>(y, lg[0], lg[1], lg[2],
                                                lbn[0], lbn[1], lbn[2], xp1);
    k_gemm<1><<<1536, 256, 0, stream>>>(xp1, wc, cb[0], cb[1], cb[2],
                                        lg[0], lg[1], lg[2], lw[0], lw[1], lw[2],
                                        y, part);
    k_fin<<<192, 256, 0, stream>>>(part, lg[0], lg[1], lg[2],
                                   lbn[0], lbn[1], lbn[2],
                                   lw[0], lw[1], lw[2],
                                   lbias[0], lbias[1], lbias[2],
                                   mask, logd_out, pitch_out, energy_out);
}